// Round 1
// baseline (2713.024 us; speedup 1.0000x reference)
//
#include <hip/hip_runtime.h>
#include <hip/hip_bf16.h>
#include <math.h>

typedef __bf16 bf16x8 __attribute__((ext_vector_type(8)));
typedef float f32x4 __attribute__((ext_vector_type(4)));

__device__ inline unsigned short f2b(float f) {
  union { float f; unsigned u; } v; v.f = f;
  unsigned u = v.u;
  return (unsigned short)((u + 0x7fffu + ((u >> 16) & 1u)) >> 16);
}
__device__ inline float b2f(unsigned short s) {
  union { unsigned u; float f; } v; v.u = ((unsigned)s) << 16;
  return v.f;
}
__device__ inline float sigm(float x) { return 1.f / (1.f + __expf(-x)); }
__device__ inline float tanh_f(float x) {
  float e = __expf(2.f * x);
  return 1.f - 2.f / (e + 1.f);
}

// -------------------- prep: weights->bf16, h init --------------------
__global__ __launch_bounds__(256) void prep_kernel(
    const float* __restrict__ Wih, const float* __restrict__ Whh,
    const float* __restrict__ c, unsigned short* __restrict__ Wihb,
    unsigned short* __restrict__ Whhb, unsigned short* __restrict__ hbf,
    float* __restrict__ h32, long nW, long nH)
{
  long stride = (long)gridDim.x * blockDim.x;
  long t0 = (long)blockIdx.x * blockDim.x + threadIdx.x;
  for (long i = t0; i < nW; i += stride) {
    Wihb[i] = f2b(Wih[i]);
    Whhb[i] = f2b(Whh[i]);
  }
  for (long i = t0; i < nH; i += stride) {
    float v = c[i];
    h32[i] = v;
    hbf[i] = f2b(v);
  }
}

// -------------------- transpose x (B,E,K) -> XS (K,B,E) bf16 ----------
// XS[0] is zeroed separately (memset); XS[k+1][b][e] = x[b][e][k], k<K-1.
// Assumes K == 64, E % 64 == 0.
__global__ __launch_bounds__(256) void transpose_x(
    const float* __restrict__ x, unsigned short* __restrict__ XS,
    int B, int E, int K)
{
  __shared__ float T[64][65];
  int e0 = blockIdx.x * 64;
  int b = blockIdx.y;
  int t = threadIdx.x;
  const float* xb = x + ((long)b * E + e0) * K;
#pragma unroll
  for (int i = 0; i < 4; ++i) {
    int cidx = i * 256 + t;          // 1024 float4 chunks
    int e = cidx >> 4;               // 16 float4 per row (K=64)
    int f4 = cidx & 15;
    float4 v = *(const float4*)(xb + (long)e * K + f4 * 4);
    T[e][f4 * 4 + 0] = v.x;
    T[e][f4 * 4 + 1] = v.y;
    T[e][f4 * 4 + 2] = v.z;
    T[e][f4 * 4 + 3] = v.w;
  }
  __syncthreads();
#pragma unroll
  for (int i = 0; i < 16; ++i) {
    int cidx = i * 256 + t;          // 4096 elems: k = c>>6, e = c&63
    int k = cidx >> 6;
    int e = cidx & 63;
    if (k < K - 1)
      XS[((long)(k + 1) * B + b) * E + e0 + e] = f2b(T[e][k]);
  }
}

// -------------------- GEMM: C(M,N) = A(M,K) @ Bw(N,K)^T + bias --------
// A, Bw bf16 (ushort); OUTBF=1 -> bf16 out (Cb), else fp32 out (Cf).
// 128x128 tile, BK=64, 256 threads (4 waves, 2x2), global_load_lds w=16,
// T2 XOR swizzle applied source-side (rule #21), bijective XCD swizzle.
#define BM 128
#define BN 128
#define BKS 64

template<int OUTBF>
__global__ __launch_bounds__(256)
void gemm_bt(const unsigned short* __restrict__ A,
             const unsigned short* __restrict__ Bw,
             const float* __restrict__ bias,
             float* __restrict__ Cf, unsigned short* __restrict__ Cb,
             int M, int N, int K)
{
  __shared__ __align__(16) unsigned short As[BM * BKS];
  __shared__ __align__(16) unsigned short Bs[BN * BKS];

  int nwg = gridDim.x * gridDim.y;
  int wg = blockIdx.y * gridDim.x + blockIdx.x;
  if ((nwg & 7) == 0) { int ch = nwg >> 3; wg = (wg & 7) * ch + (wg >> 3); }
  int tx = wg % gridDim.x;   // N tile
  int ty = wg / gridDim.x;   // M tile

  const int tid = threadIdx.x;
  const int lane = tid & 63;
  const int wave = tid >> 6;
  const int wr = wave >> 1, wc = wave & 1;

  f32x4 acc[4][4] = {};

  const long a_base = (long)ty * BM * K;
  const long b_base = (long)tx * BN * K;

  for (int kt = 0; kt < K; kt += BKS) {
    __syncthreads();
#pragma unroll
    for (int i = 0; i < 4; ++i) {
      int c = i * 256 + tid;
      int row = c >> 3, sc = c & 7;
      int gcol8 = sc ^ (row & 7);   // source-side swizzle (involution)
      const unsigned short* ga = A + a_base + (long)row * K + kt + gcol8 * 8;
      const unsigned short* gb = Bw + b_base + (long)row * K + kt + gcol8 * 8;
      int cbase = (i * 256 + wave * 64) * 8;  // ushort offset, wave-uniform
      __builtin_amdgcn_global_load_lds(
          (const __attribute__((address_space(1))) void*)ga,
          (__attribute__((address_space(3))) void*)&As[cbase], 16, 0, 0);
      __builtin_amdgcn_global_load_lds(
          (const __attribute__((address_space(1))) void*)gb,
          (__attribute__((address_space(3))) void*)&Bs[cbase], 16, 0, 0);
    }
    __syncthreads();
#pragma unroll
    for (int kk = 0; kk < BKS; kk += 32) {
      int kidx = kk + ((lane >> 4) << 3);
      int c8 = kidx >> 3;
      bf16x8 af[4], bfv[4];
#pragma unroll
      for (int m = 0; m < 4; ++m) {
        int row = wr * 64 + m * 16 + (lane & 15);
        af[m] = *(const bf16x8*)&As[row * BKS + ((c8 ^ (row & 7)) << 3)];
      }
#pragma unroll
      for (int n = 0; n < 4; ++n) {
        int col = wc * 64 + n * 16 + (lane & 15);
        bfv[n] = *(const bf16x8*)&Bs[col * BKS + ((c8 ^ (col & 7)) << 3)];
      }
#pragma unroll
      for (int m = 0; m < 4; ++m)
#pragma unroll
        for (int n = 0; n < 4; ++n)
          acc[m][n] = __builtin_amdgcn_mfma_f32_16x16x32_bf16(
              af[m], bfv[n], acc[m][n], 0, 0, 0);
    }
  }

  long crow0 = (long)ty * BM + wr * 64;
  long ccol0 = (long)tx * BN + wc * 64;
#pragma unroll
  for (int m = 0; m < 4; ++m) {
#pragma unroll
    for (int n = 0; n < 4; ++n) {
      long col = ccol0 + n * 16 + (lane & 15);
      float bv = bias[col];
#pragma unroll
      for (int j = 0; j < 4; ++j) {
        long row = crow0 + m * 16 + ((lane >> 4) << 2) + j;
        float v = acc[m][n][j] + bv;
        if (OUTBF) Cb[row * N + col] = f2b(v);
        else       Cf[row * N + col] = v;
      }
    }
  }
}

// -------------------- pointwise GRU gates -----------------------------
// YMODE 0: Y fp32 (K,B,E); 1: Y bf16 (K,B,E); 2: scattered direct out.
template<int YMODE>
__global__ __launch_bounds__(256)
void gru_pointwise(const unsigned short* __restrict__ GIk,
                   const float* __restrict__ gh,
                   float* __restrict__ h, unsigned short* __restrict__ hbf,
                   float* __restrict__ Yf, unsigned short* __restrict__ Yb,
                   float* __restrict__ out, int k, int B, int E, int K)
{
  long i4 = ((long)blockIdx.x * blockDim.x + threadIdx.x) * 4;
  if (i4 >= (long)B * E) return;
  long b = i4 / E;
  long e = i4 - b * E;
  long g0 = b * 3 * E + e;
  ushort4 ir = *(const ushort4*)(GIk + g0);
  ushort4 iz = *(const ushort4*)(GIk + g0 + E);
  ushort4 in4 = *(const ushort4*)(GIk + g0 + 2 * E);
  float4 hr = *(const float4*)(gh + g0);
  float4 hz = *(const float4*)(gh + g0 + E);
  float4 hn = *(const float4*)(gh + g0 + 2 * E);
  float4 hv = *(const float4*)(h + i4);

  float irf[4] = { b2f(ir.x), b2f(ir.y), b2f(ir.z), b2f(ir.w) };
  float izf[4] = { b2f(iz.x), b2f(iz.y), b2f(iz.z), b2f(iz.w) };
  float inf_[4] = { b2f(in4.x), b2f(in4.y), b2f(in4.z), b2f(in4.w) };
  float hrf[4] = { hr.x, hr.y, hr.z, hr.w };
  float hzf[4] = { hz.x, hz.y, hz.z, hz.w };
  float hnf[4] = { hn.x, hn.y, hn.z, hn.w };
  float hvf[4] = { hv.x, hv.y, hv.z, hv.w };
  float hnew[4];
#pragma unroll
  for (int j = 0; j < 4; ++j) {
    float r = sigm(irf[j] + hrf[j]);
    float z = sigm(izf[j] + hzf[j]);
    float n = tanh_f(inf_[j] + r * hnf[j]);
    hnew[j] = (1.f - z) * n + z * hvf[j];
  }
  *(float4*)(h + i4) = make_float4(hnew[0], hnew[1], hnew[2], hnew[3]);
  ushort4 hb = make_ushort4(f2b(hnew[0]), f2b(hnew[1]), f2b(hnew[2]), f2b(hnew[3]));
  *(ushort4*)(hbf + i4) = hb;
  if (YMODE == 0) {
    *(float4*)(Yf + ((long)k * B + b) * E + e) =
        make_float4(hnew[0], hnew[1], hnew[2], hnew[3]);
  } else if (YMODE == 1) {
    *(ushort4*)(Yb + ((long)k * B + b) * E + e) = hb;
  } else {
    float* o = out + (b * E + e) * K + k;
    o[0] = hnew[0]; o[K] = hnew[1]; o[2 * K] = hnew[2]; o[3 * K] = hnew[3];
  }
}

// -------------------- transpose Y (K,B,E) -> out (B,E,K) fp32 ---------
// Assumes K == 64, E % 64 == 0.
template<int YB>  // 0: Y fp32, 1: Y bf16
__global__ __launch_bounds__(256)
void transpose_y(const void* __restrict__ Yv, float* __restrict__ out,
                 int B, int E, int K)
{
  __shared__ float T[64][65];  // [k][e]
  int e0 = blockIdx.x * 64;
  int b = blockIdx.y;
  int t = threadIdx.x;
#pragma unroll
  for (int i = 0; i < 4; ++i) {
    int c = i * 256 + t;   // 1024 chunks: k = c>>4, f4 = c&15
    int k = c >> 4, f4 = c & 15;
    long off = ((long)k * B + b) * E + e0 + f4 * 4;
    if (YB == 0) {
      float4 v = *(const float4*)((const float*)Yv + off);
      T[k][f4 * 4 + 0] = v.x; T[k][f4 * 4 + 1] = v.y;
      T[k][f4 * 4 + 2] = v.z; T[k][f4 * 4 + 3] = v.w;
    } else {
      ushort4 v = *(const ushort4*)((const unsigned short*)Yv + off);
      T[k][f4 * 4 + 0] = b2f(v.x); T[k][f4 * 4 + 1] = b2f(v.y);
      T[k][f4 * 4 + 2] = b2f(v.z); T[k][f4 * 4 + 3] = b2f(v.w);
    }
  }
  __syncthreads();
#pragma unroll
  for (int i = 0; i < 4; ++i) {
    int c = i * 256 + t;   // 1024 chunks: e = c>>4, f4k = c&15
    int e = c >> 4, f4k = c & 15;
    float4 w;
    w.x = T[f4k * 4 + 0][e];
    w.y = T[f4k * 4 + 1][e];
    w.z = T[f4k * 4 + 2][e];
    w.w = T[f4k * 4 + 3][e];
    *(float4*)(out + ((long)b * E + e0 + e) * K + f4k * 4) = w;
  }
}

// -------------------- host launch -------------------------------------
extern "C" void kernel_launch(void* const* d_in, const int* in_sizes, int n_in,
                              void* d_out, int out_size, void* d_ws, size_t ws_size,
                              hipStream_t stream)
{
  const float* c   = (const float*)d_in[0];
  const float* x   = (const float*)d_in[1];
  const float* Wih = (const float*)d_in[2];
  const float* Whh = (const float*)d_in[3];
  const float* bih = (const float*)d_in[4];
  const float* bhh = (const float*)d_in[5];
  float* out = (float*)d_out;

  long BE = in_sizes[0];
  int E = (int)(sqrtf((float)(in_sizes[2] / 3)) + 0.5f);
  int B = (int)(BE / E);
  int K = (int)(in_sizes[1] / BE);
  int N3 = 3 * E;
  long M_GI = (long)K * B;

  char* w = (char*)d_ws;
  size_t used = 0;
  auto alloc = [&](size_t bytes) -> char* {
    char* p = w + used;
    used += (bytes + 255) & ~(size_t)255;
    return p;
  };
  unsigned short* Wihb  = (unsigned short*)alloc((size_t)N3 * E * 2);
  unsigned short* Whhb  = (unsigned short*)alloc((size_t)N3 * E * 2);
  unsigned short* hbf   = (unsigned short*)alloc((size_t)B * E * 2);
  float* h32            = (float*)alloc((size_t)B * E * 4);
  float* gh             = (float*)alloc((size_t)B * N3 * 4);
  unsigned short* GIstep= (unsigned short*)alloc((size_t)B * N3 * 2);
  unsigned short* XS    = (unsigned short*)alloc((size_t)K * B * E * 2);

  size_t rem = (ws_size > used) ? ws_size - used : 0;
  size_t giFull = (((size_t)K * B * N3 * 2) + 255) & ~(size_t)255;
  size_t yF = (((size_t)K * B * E * 4) + 255) & ~(size_t)255;
  size_t yB = (((size_t)K * B * E * 2) + 255) & ~(size_t)255;

  int fullGI = 0, ymode = 2;
  unsigned short* GI = GIstep;
  float* Yf = nullptr;
  unsigned short* Yb = nullptr;
  if (rem >= giFull + yF) {
    fullGI = 1; ymode = 0;
    GI = (unsigned short*)alloc(giFull);
    Yf = (float*)alloc(yF);
  } else if (rem >= giFull + yB) {
    fullGI = 1; ymode = 1;
    GI = (unsigned short*)alloc(giFull);
    Yb = (unsigned short*)alloc(yB);
  } else if (rem >= yB) {
    fullGI = 0; ymode = 1;
    Yb = (unsigned short*)alloc(yB);
  } else {
    fullGI = 0; ymode = 2;
  }

  long nW = (long)N3 * E;
  prep_kernel<<<dim3(2048), dim3(256), 0, stream>>>(Wih, Whh, c, Wihb, Whhb,
                                                    hbf, h32, nW, BE);
  hipMemsetAsync(XS, 0, (size_t)B * E * 2, stream);  // XS[0] = zeros
  transpose_x<<<dim3(E / 64, B), dim3(256), 0, stream>>>(x, XS, B, E, K);

  if (fullGI) {
    gemm_bt<1><<<dim3(N3 / BN, (int)(M_GI / BM)), dim3(256), 0, stream>>>(
        XS, Wihb, bih, nullptr, GI, (int)M_GI, N3, E);
  }

  int pgrid = (int)((BE / 4 + 255) / 256);
  for (int k = 0; k < K; ++k) {
    if (!fullGI) {
      gemm_bt<1><<<dim3(N3 / BN, B / BM), dim3(256), 0, stream>>>(
          XS + (size_t)k * B * E, Wihb, bih, nullptr, GIstep, B, N3, E);
    }
    gemm_bt<0><<<dim3(N3 / BN, B / BM), dim3(256), 0, stream>>>(
        hbf, Whhb, bhh, gh, nullptr, B, N3, E);
    const unsigned short* GIk = fullGI ? GI + (size_t)k * B * N3 : GIstep;
    if (ymode == 0)
      gru_pointwise<0><<<dim3(pgrid), dim3(256), 0, stream>>>(
          GIk, gh, h32, hbf, Yf, nullptr, out, k, B, E, K);
    else if (ymode == 1)
      gru_pointwise<1><<<dim3(pgrid), dim3(256), 0, stream>>>(
          GIk, gh, h32, hbf, nullptr, Yb, out, k, B, E, K);
    else
      gru_pointwise<2><<<dim3(pgrid), dim3(256), 0, stream>>>(
          GIk, gh, h32, hbf, nullptr, nullptr, out, k, B, E, K);
  }

  if (ymode == 0)
    transpose_y<0><<<dim3(E / 64, B), dim3(256), 0, stream>>>(Yf, out, B, E, K);
  else if (ymode == 1)
    transpose_y<1><<<dim3(E / 64, B), dim3(256), 0, stream>>>(Yb, out, B, E, K);
}